// Round 3
// baseline (697.696 us; speedup 1.0000x reference)
//
#include <hip/hip_runtime.h>

#define BB 1024
#define TT 512
#define KK 64

// ---------------- setup: zero loss + snake-balanced length sort ----------------
__global__ void crf_setup(const int* __restrict__ nwords,
                          int* __restrict__ rank2batch,
                          float* __restrict__ out) {
    __shared__ int hist[TT];              // key = TT - len  (descending length order)
    const int tid = threadIdx.x;          // 512 threads
    if (tid < TT) hist[tid] = 0;
    __syncthreads();
    for (int b = tid; b < BB; b += 512)
        atomicAdd(&hist[TT - nwords[b]], 1);
    __syncthreads();
    if (tid == 0) {
        int run = 0;
        for (int k = 0; k < TT; ++k) { int c = hist[k]; hist[k] = run; run += c; }
        out[(size_t)BB * TT] = 0.0f;      // zero the loss accumulator
    }
    __syncthreads();
    for (int b = tid; b < BB; b += 512) {
        int r = atomicAdd(&hist[TT - nwords[b]], 1);
        rank2batch[r] = b;
    }
}

// combine (v,i) candidates; ties -> lower index (jnp.argmax first-occurrence)
#define COMB(v, i, v2, i2)                                   \
    { bool _t = ((v2) > (v)) || ((v2) == (v) && (i2) < (i)); \
      (v) = _t ? (v2) : (v); (i) = _t ? (i2) : (i); }

__global__ __launch_bounds__(128, 1)
void crf_fwd_kernel(const float* __restrict__ logits,
                    const int* __restrict__ nwords,
                    const int* __restrict__ tags,
                    const float* __restrict__ trans,
                    const int* __restrict__ rank2batch,
                    float* __restrict__ out) {
    __shared__ __align__(16) float sA[KK];        // viterbi alpha broadcast
    __shared__ __align__(16) float sP[KK];        // lse p broadcast
    __shared__ unsigned char sBP[TT * KK];        // backpointers
    __shared__ unsigned char sTag[TT];

    const int bid  = blockIdx.x;
    const int cu   = bid & 255, slot = bid >> 8;  // snake: balance sum(len) per CU
    const int r    = (slot == 0) ? cu : (slot == 1) ? (511 - cu)
                   : (slot == 2) ? (512 + cu) : (1023 - cu);
    const int b    = rank2batch[r];

    const int tid  = threadIdx.x;
    const int lane = tid & 63;
    const int wid  = tid >> 6;
    const int m    = lane & 31;                   // j-pair: j0=2m, j1=2m+1
    const int h    = lane >> 5;                   // i-half: i in [32h, 32h+32)
    const int len  = nwords[b];
    const float*  lg  = logits + (size_t)b * TT * KK;
    const float2* lg2 = (const float2*)lg;        // lg2[t*32 + m] = logits[t][2m..2m+1]
    const float2* tr2 = (const float2*)trans;     // tr2[i*32 + m] = trans[i][2m..2m+1]

    if (wid == 0) {
        // ---------------- Viterbi wave ----------------
        float tA[32], tB[32];                     // trans[32h+i][2m], [2m+1]
#pragma unroll
        for (int i = 0; i < 32; ++i) {
            float2 t2 = tr2[(32 * h + i) * 32 + m];
            tA[i] = t2.x; tB[i] = t2.y;
        }

        float2 lgt = lg2[m];                      // t = 0
        float a0 = lgt.x, a1 = lgt.y;
        if (h == 0) ((float2*)sA)[m] = make_float2(a0, a1);

        float2 lgt_nxt = lg2[32 * min(1, len - 1) + m];
        for (int t = 1; t < len; ++t) {
            lgt = lgt_nxt;
            lgt_nxt = lg2[32 * min(t + 1, len - 1) + m];

            float4 a4[8];
#pragma unroll
            for (int q = 0; q < 8; ++q) a4[q] = ((const float4*)sA)[h * 8 + q];

            // ---- j0 : 4-slot scan (ascending index within slot) ----
            float bx, by, bz, bw; int ix, iy, iz, iw;
            {
                int base = 32 * h;
                bx = a4[0].x + tA[0]; ix = base;
                by = a4[0].y + tA[1]; iy = base + 1;
                bz = a4[0].z + tA[2]; iz = base + 2;
                bw = a4[0].w + tA[3]; iw = base + 3;
#pragma unroll
                for (int q = 1; q < 8; ++q) {
                    int ib = base + 4 * q;
                    float sx = a4[q].x + tA[4*q+0]; if (sx > bx) { bx = sx; ix = ib; }
                    float sy = a4[q].y + tA[4*q+1]; if (sy > by) { by = sy; iy = ib+1; }
                    float sz = a4[q].z + tA[4*q+2]; if (sz > bz) { bz = sz; iz = ib+2; }
                    float sw = a4[q].w + tA[4*q+3]; if (sw > bw) { bw = sw; iw = ib+3; }
                }
                COMB(bx, ix, by, iy); COMB(bx, ix, bz, iz); COMB(bx, ix, bw, iw);
            }
            float pv0 = __shfl_xor(bx, 32); int pi0 = __shfl_xor(ix, 32);
            COMB(bx, ix, pv0, pi0);
            a0 = bx + lgt.x;
            int bp0 = ix;

            // ---- j1 ----
            {
                int base = 32 * h;
                bx = a4[0].x + tB[0]; ix = base;
                by = a4[0].y + tB[1]; iy = base + 1;
                bz = a4[0].z + tB[2]; iz = base + 2;
                bw = a4[0].w + tB[3]; iw = base + 3;
#pragma unroll
                for (int q = 1; q < 8; ++q) {
                    int ib = base + 4 * q;
                    float sx = a4[q].x + tB[4*q+0]; if (sx > bx) { bx = sx; ix = ib; }
                    float sy = a4[q].y + tB[4*q+1]; if (sy > by) { by = sy; iy = ib+1; }
                    float sz = a4[q].z + tB[4*q+2]; if (sz > bz) { bz = sz; iz = ib+2; }
                    float sw = a4[q].w + tB[4*q+3]; if (sw > bw) { bw = sw; iw = ib+3; }
                }
                COMB(bx, ix, by, iy); COMB(bx, ix, bz, iz); COMB(bx, ix, bw, iw);
            }
            float pv1 = __shfl_xor(bx, 32); int pi1 = __shfl_xor(ix, 32);
            COMB(bx, ix, pv1, pi1);
            a1 = bx + lgt.y;
            int bp1 = ix;

            if (h == 0) {
                ((unsigned short*)sBP)[t * 32 + m] =
                    (unsigned short)((bp0 & 0xff) | ((bp1 & 0xff) << 8));
                ((float2*)sA)[m] = make_float2(a0, a1);
            }
        }

        // last = first-occurrence argmax over 64 tags
        float bv = a0; int bj = 2 * m;
        { float v2 = a1; int i2 = 2 * m + 1; COMB(bv, bj, v2, i2); }
#pragma unroll
        for (int msk = 1; msk <= 16; msk <<= 1) {
            float ov = __shfl_xor(bv, msk); int oj = __shfl_xor(bj, msk);
            COMB(bv, bj, ov, oj);
        }
        const int last = bj;                       // wave-uniform

        for (int t = len - 1 + lane; t < TT; t += 64)
            out[(size_t)b * TT + t] = (float)last;

        int tag = last;
        for (int t = len - 1; t >= 1; --t) {
            tag = sBP[t * KK + tag];
            sTag[t - 1] = (unsigned char)tag;
        }
        for (int t = lane; t < len - 1; t += 64)
            out[(size_t)b * TT + t] = (float)sTag[t];

    } else {
        // ---------------- logsumexp + score wave ----------------
        float eA[32], eB[32];                      // exp(trans[32h+i][2m]), [2m+1]
#pragma unroll
        for (int i = 0; i < 32; ++i) {
            float2 t2 = tr2[(32 * h + i) * 32 + m];
            eA[i] = __expf(t2.x); eB[i] = __expf(t2.y);
        }

        float2 lgt = lg2[m];                       // t = 0
        float a0 = lgt.x, a1 = lgt.y;
        float C = 0.0f;
        int tg = tags[b * TT];
        float acc = 0.0f;
        if (h == 0) { if (tg == 2*m) acc = lgt.x; else if (tg == 2*m+1) acc = lgt.y; }
        int tprev = tg;

        float2 lgt_nxt = lg2[32 * min(1, len - 1) + m];
        for (int t = 1; t < len; ++t) {
            lgt = lgt_nxt;
            lgt_nxt = lg2[32 * min(t + 1, len - 1) + m];

            // wave max M over all 64 alphas (halves replicated)
            float M = fmaxf(a0, a1);
#pragma unroll
            for (int msk = 1; msk <= 16; msk <<= 1) M = fmaxf(M, __shfl_xor(M, msk));

            float p0 = __expf(a0 - M), p1 = __expf(a1 - M);
            if (h == 0) ((float2*)sP)[m] = make_float2(p0, p1);

            float sx0 = 0.f, sy0 = 0.f, sz0 = 0.f, sw0 = 0.f;
            float sx1 = 0.f, sy1 = 0.f, sz1 = 0.f, sw1 = 0.f;
#pragma unroll
            for (int q = 0; q < 8; ++q) {
                float4 p4 = ((const float4*)sP)[h * 8 + q];
                sx0 = fmaf(p4.x, eA[4*q+0], sx0); sy0 = fmaf(p4.y, eA[4*q+1], sy0);
                sz0 = fmaf(p4.z, eA[4*q+2], sz0); sw0 = fmaf(p4.w, eA[4*q+3], sw0);
                sx1 = fmaf(p4.x, eB[4*q+0], sx1); sy1 = fmaf(p4.y, eB[4*q+1], sy1);
                sz1 = fmaf(p4.z, eB[4*q+2], sz1); sw1 = fmaf(p4.w, eB[4*q+3], sw1);
            }
            float S0 = (sx0 + sy0) + (sz0 + sw0);
            float S1 = (sx1 + sy1) + (sz1 + sw1);
            S0 += __shfl_xor(S0, 32);              // add other i-half
            S1 += __shfl_xor(S1, 32);

            a0 = __logf(S0) + lgt.x;
            a1 = __logf(S1) + lgt.y;
            C += M;

            tg = tags[b * TT + t];
            if (h == 0) { if (tg == 2*m) acc += lgt.x; else if (tg == 2*m+1) acc += lgt.y; }
            if (lane == 0) acc += trans[tprev * KK + tg];
            tprev = tg;
        }

        // log_norm = C + logsumexp over 64 alphas
        float Mf = fmaxf(a0, a1);
#pragma unroll
        for (int msk = 1; msk <= 16; msk <<= 1) Mf = fmaxf(Mf, __shfl_xor(Mf, msk));
        float e = __expf(a0 - Mf) + __expf(a1 - Mf);
#pragma unroll
        for (int msk = 1; msk <= 16; msk <<= 1) e += __shfl_xor(e, msk);
        const float log_norm = C + Mf + __logf(e);

#pragma unroll
        for (int msk = 1; msk <= 32; msk <<= 1) acc += __shfl_xor(acc, msk);

        if (lane == 0)
            atomicAdd(out + (size_t)BB * TT, (log_norm - acc) * (1.0f / BB));
    }
}

extern "C" void kernel_launch(void* const* d_in, const int* in_sizes, int n_in,
                              void* d_out, int out_size, void* d_ws, size_t ws_size,
                              hipStream_t stream) {
    const float* logits = (const float*)d_in[0];
    const int*   nwords = (const int*)d_in[1];
    const int*   tags   = (const int*)d_in[2];
    const float* trans  = (const float*)d_in[3];
    float*       out    = (float*)d_out;
    int*         rank2batch = (int*)d_ws;

    crf_setup<<<1, 512, 0, stream>>>(nwords, rank2batch, out);
    crf_fwd_kernel<<<BB, 128, 0, stream>>>(logits, nwords, tags, trans, rank2batch, out);
}

// Round 5
// 651.110 us; speedup vs baseline: 1.0715x; 1.0715x over previous
//
#include <hip/hip_runtime.h>

#define BB 1024
#define TT 512
#define KK 64

// ---------------- setup: zero loss + length-sort (descending) ----------------
__global__ void crf_setup(const int* __restrict__ nwords,
                          int* __restrict__ rank2batch,
                          float* __restrict__ out) {
    __shared__ int hist[TT];
    const int tid = threadIdx.x;              // 256 threads
    for (int k = tid; k < TT; k += 256) hist[k] = 0;
    __syncthreads();
    for (int b = tid; b < BB; b += 256) atomicAdd(&hist[TT - nwords[b]], 1);
    __syncthreads();
    if (tid < 64) {                           // wave 0: parallel exclusive prefix over 512 bins
        int s = 0;
#pragma unroll
        for (int k = 0; k < 8; ++k) s += hist[tid * 8 + k];
        int incl = s;
        for (int d = 1; d < 64; d <<= 1) { int o = __shfl_up(incl, d); if (tid >= d) incl += o; }
        int run = incl - s;                   // exclusive
#pragma unroll
        for (int k = 0; k < 8; ++k) { int c = hist[tid * 8 + k]; hist[tid * 8 + k] = run; run += c; }
    }
    if (tid == 0) out[(size_t)BB * TT] = 0.0f;
    __syncthreads();
    for (int b = tid; b < BB; b += 256) {
        int r = atomicAdd(&hist[TT - nwords[b]], 1);
        rank2batch[r] = b;
    }
}

// combine (v,i); ties -> lower index (jnp.argmax first-occurrence)
#define COMB(v, i, v2, i2)                                   \
    { bool _t = ((v2) > (v)) || ((v2) == (v) && (i2) < (i)); \
      (v) = _t ? (v2) : (v); (i) = _t ? (i2) : (i); }

__global__ __launch_bounds__(128, 1)
void crf_fwd_kernel(const float* __restrict__ logits,
                    const int* __restrict__ nwords,
                    const int* __restrict__ tags,
                    const float* __restrict__ trans,
                    const int* __restrict__ rank2batch,
                    float* __restrict__ out) {
    __shared__ __align__(16) float sA[KK];        // viterbi alpha broadcast
    __shared__ __align__(16) float sU[KK];        // exp-domain lse state broadcast
    __shared__ unsigned char sBP[TT * KK];        // backpointers
    __shared__ unsigned char sTag[TT];

    const int bid  = blockIdx.x;
    const int cu   = bid & 255, slot = bid >> 8;  // snake: balance sum(len) per CU
    const int r    = (slot == 0) ? cu : (slot == 1) ? (511 - cu)
                   : (slot == 2) ? (512 + cu) : (1023 - cu);
    const int b    = rank2batch[r];

    const int lane = threadIdx.x & 63;
    const int wid  = threadIdx.x >> 6;
    const int len  = nwords[b];
    const float* lg = logits + (size_t)b * TT * KK;

    if (wid == 0) {
        // ---------------- Viterbi wave (R1 structure + 2-ahead prefetch) ----------------
        float tc[KK];
#pragma unroll
        for (int i = 0; i < KK; ++i) tc[i] = trans[i * KK + lane];

        float alpha = lg[lane];               // t = 0
        sA[lane] = alpha;

        float f1 = lg[(len > 1 ? 1 : 0) * KK + lane];
        float f2 = lg[(len > 2 ? 2 : (len - 1)) * KK + lane];

        for (int t = 1; t < len; ++t) {
            const float logit = f1;           // row t (prefetched 2 steps ago)
            f1 = f2;
            int tn = t + 2; if (tn > len - 1) tn = len - 1;
            f2 = lg[tn * KK + lane];          // issue early; no dependency on this step

            float4 aq = ((const float4*)sA)[0];
            float bx = aq.x + tc[0]; int ix = 0;
            float by = aq.y + tc[1]; int iy = 1;
            float bz = aq.z + tc[2]; int iz = 2;
            float bw = aq.w + tc[3]; int iw = 3;
#pragma unroll
            for (int q = 1; q < 16; ++q) {
                float4 a4 = ((const float4*)sA)[q];
                float sx = a4.x + tc[4*q+0]; if (sx > bx) { bx = sx; ix = 4*q+0; }
                float sy = a4.y + tc[4*q+1]; if (sy > by) { by = sy; iy = 4*q+1; }
                float sz = a4.z + tc[4*q+2]; if (sz > bz) { bz = sz; iz = 4*q+2; }
                float sw = a4.w + tc[4*q+3]; if (sw > bw) { bw = sw; iw = 4*q+3; }
            }
            COMB(bx, ix, by, iy); COMB(bz, iz, bw, iw); COMB(bx, ix, bz, iz);

            alpha = bx + logit;
            sBP[t * KK + lane] = (unsigned char)ix;
            sA[lane] = alpha;                 // same-wave LDS ops are in-order
        }

        // last = first-occurrence argmax over lanes of alpha
        float v = alpha; int idx = lane;
#pragma unroll
        for (int m = 32; m >= 1; m >>= 1) {
            float ov = __shfl_xor(v, m); int oi = __shfl_xor(idx, m);
            COMB(v, idx, ov, oi);
        }
        const int last = idx;                 // wave-uniform

        for (int t = len - 1 + lane; t < TT; t += 64)
            out[(size_t)b * TT + t] = (float)last;

        int tag = last;
        for (int t = len - 1; t >= 1; --t) {
            tag = sBP[t * KK + tag];
            sTag[t - 1] = (unsigned char)tag;
        }
        for (int t = lane; t < len - 1; t += 64)
            out[(size_t)b * TT + t] = (float)sTag[t];

    } else {
        // ---------------- exp-domain LSE + score wave ----------------
        float E[KK];
#pragma unroll
        for (int i = 0; i < KK; ++i) E[i] = __expf(trans[i * KK + lane]);

        const float lg0 = lg[lane];
        float M = lg0;
#pragma unroll
        for (int m = 32; m >= 1; m >>= 1) M = fmaxf(M, __shfl_xor(M, m));
        float C = M;                          // accumulated log-offset (wave-uniform)
        float u = __expf(lg0 - M);            // u[lane] = exp(alpha[lane] - C)
        sU[lane] = u;

        int tprev = tags[b * TT];
        float acc = (lane == tprev) ? lg0 : 0.0f;

        float f1 = lg[(len > 1 ? 1 : 0) * KK + lane];
        float f2 = lg[(len > 2 ? 2 : (len - 1)) * KK + lane];
        int tg1 = tags[b * TT + (len > 1 ? 1 : 0)];
        int tg2 = tags[b * TT + (len > 2 ? 2 : (len - 1))];

        for (int t = 1; t < len; ++t) {
            const float logit = f1; f1 = f2;
            const int tg = tg1; tg1 = tg2;
            int tn = t + 2; if (tn > len - 1) tn = len - 1;
            f2  = lg[tn * KK + lane];
            tg2 = tags[b * TT + tn];

            float s0 = 0.f, s1 = 0.f, s2 = 0.f, s3 = 0.f;
#pragma unroll
            for (int q = 0; q < 16; ++q) {
                float4 u4 = ((const float4*)sU)[q];
                s0 = fmaf(u4.x, E[4*q+0], s0);
                s1 = fmaf(u4.y, E[4*q+1], s1);
                s2 = fmaf(u4.z, E[4*q+2], s2);
                s3 = fmaf(u4.w, E[4*q+3], s3);
            }
            u = ((s0 + s1) + (s2 + s3)) * __expf(logit);

            if ((t & 7) == 0) {               // deferred rescale: growth ≤ ~8*(4.4+maxlogit) << 88
                float mx = u;
#pragma unroll
                for (int m = 32; m >= 1; m >>= 1) mx = fmaxf(mx, __shfl_xor(mx, m));
                u *= (1.0f / mx);
                C += __logf(mx);
            }
            sU[lane] = u;

            if (lane == tg) acc += logit;                    // unary
            if (lane == 0)  acc += trans[tprev * KK + tg];   // binary
            tprev = tg;
        }

        // log_norm = C + logsumexp(u in log domain)
        float mx = u;
#pragma unroll
        for (int m = 32; m >= 1; m >>= 1) mx = fmaxf(mx, __shfl_xor(mx, m));
        float e = u * (1.0f / mx);
#pragma unroll
        for (int m = 32; m >= 1; m >>= 1) e += __shfl_xor(e, m);
        const float log_norm = C + __logf(mx) + __logf(e);

#pragma unroll
        for (int m = 32; m >= 1; m >>= 1) acc += __shfl_xor(acc, m);

        if (lane == 0)
            atomicAdd(out + (size_t)BB * TT, (log_norm - acc) * (1.0f / BB));
    }
}

extern "C" void kernel_launch(void* const* d_in, const int* in_sizes, int n_in,
                              void* d_out, int out_size, void* d_ws, size_t ws_size,
                              hipStream_t stream) {
    const float* logits = (const float*)d_in[0];
    const int*   nwords = (const int*)d_in[1];
    const int*   tags   = (const int*)d_in[2];
    const float* trans  = (const float*)d_in[3];
    float*       out    = (float*)d_out;
    int*         rank2batch = (int*)d_ws;

    crf_setup<<<1, 256, 0, stream>>>(nwords, rank2batch, out);
    crf_fwd_kernel<<<BB, 128, 0, stream>>>(logits, nwords, tags, trans, rank2batch, out);
}